// Round 13
// baseline (370.366 us; speedup 1.0000x reference)
//
#include <hip/hip_runtime.h>
#include <hip/hip_bf16.h>
#include <math.h>

#define H 64
#define FIN 512
#define COUT 40

typedef __attribute__((ext_vector_type(8))) short bf16x8;
typedef __attribute__((ext_vector_type(4))) float f32x4;

__device__ __forceinline__ unsigned short f2bf(float f) {
    union { float f; unsigned u; } v; v.f = f;
    unsigned r = v.u + 0x7FFF + ((v.u >> 16) & 1);   // RNE
    return (unsigned short)(r >> 16);
}
__device__ __forceinline__ float bflo(unsigned u) { return __uint_as_float(u << 16); }
__device__ __forceinline__ float bfhi(unsigned u) { return __uint_as_float(u & 0xffff0000u); }

// ---------- unified weight pack: Bp (W_in), Bc0/Bc1 (layers), Bo (W_out, 48-col padded) ----------
__global__ void k_pack(const float* __restrict__ W_in,
                       const float* __restrict__ W1_0, const float* __restrict__ W2_0,
                       const float* __restrict__ Wf_0,
                       const float* __restrict__ W1_1, const float* __restrict__ W2_1,
                       const float* __restrict__ Wf_1,
                       const float* __restrict__ W_out,
                       uint4* __restrict__ Bp, uint4* __restrict__ Bc0,
                       uint4* __restrict__ Bc1, uint4* __restrict__ Bo) {
    int t = blockIdx.x * blockDim.x + threadIdx.x;
    const float* src;
    uint4* dst;
    if (t < 4096) {                       // W_in: 64 kb x 64 n
        int kb = t >> 6, n = t & 63;
        src = &W_in[n * FIN + kb * 8];
        dst = &Bp[t];
    } else if (t < 4096 + 1536) {         // layer 0
        int u = t - 4096;
        int j = u >> 9, kb = (u >> 6) & 7, n = u & 63;
        const float* W = (j == 0) ? W1_0 : (j == 1) ? W2_0 : Wf_0;
        src = &W[n * H + kb * 8];
        dst = &Bc0[u];
    } else if (t < 4096 + 3072) {         // layer 1
        int u = t - 4096 - 1536;
        int j = u >> 9, kb = (u >> 6) & 7, n = u & 63;
        const float* W = (j == 0) ? W1_1 : (j == 1) ? W2_1 : Wf_1;
        src = &W[n * H + kb * 8];
        dst = &Bc1[u];
    } else if (t < 4096 + 3072 + 512) {   // W_out: 8 kb x 64 cols (cols >= COUT -> 0)
        int u = t - 4096 - 3072;
        int kb = u >> 6, col = u & 63;
        if (col >= COUT) { Bo[u] = make_uint4(0u, 0u, 0u, 0u); return; }
        src = &W_out[col * H + kb * 8];
        dst = &Bo[u];
    } else return;
    float4 a0 = *(const float4*)&src[0];
    float4 a1 = *(const float4*)&src[4];
    uint4 u;
    u.x = ((unsigned)f2bf(a0.y) << 16) | f2bf(a0.x);
    u.y = ((unsigned)f2bf(a0.w) << 16) | f2bf(a0.z);
    u.z = ((unsigned)f2bf(a1.y) << 16) | f2bf(a1.x);
    u.w = ((unsigned)f2bf(a1.w) << 16) | f2bf(a1.z);
    *dst = u;
}

// ---------- CSR build ----------
__global__ void k_hist(const int* __restrict__ ei, int* __restrict__ deg, int nE) {
    int e = blockIdx.x * blockDim.x + threadIdx.x;
    if (e < nE) atomicAdd(&deg[ei[nE + e]], 1);
}

__global__ __launch_bounds__(256) void k_scan1(const int* __restrict__ deg, int* __restrict__ epos,
                                               int* __restrict__ blocksum, int n) {
    __shared__ int tmp[256];
    int t = threadIdx.x;
    int base = blockIdx.x * 1024 + t * 4;
    int v[4]; int s = 0;
#pragma unroll
    for (int i = 0; i < 4; ++i) { v[i] = (base + i < n) ? deg[base + i] : 0; s += v[i]; }
    tmp[t] = s;
    __syncthreads();
    int incl = s;
    for (int off = 1; off < 256; off <<= 1) {
        int y = (t >= off) ? tmp[t - off] : 0;
        __syncthreads();
        incl += y;
        tmp[t] = incl;
        __syncthreads();
    }
    if (t == 255) blocksum[blockIdx.x] = incl;
    int run = incl - s;
#pragma unroll
    for (int i = 0; i < 4; ++i) { if (base + i < n) epos[base + i] = run; run += v[i]; }
}

__global__ __launch_bounds__(256) void k_scan2(const int* __restrict__ blocksum,
                                               int* __restrict__ blockoff, int nb) {
    __shared__ int tmp[256];
    int t = threadIdx.x;
    int s = (t < nb) ? blocksum[t] : 0;
    tmp[t] = s;
    __syncthreads();
    int incl = s;
    for (int off = 1; off < 256; off <<= 1) {
        int y = (t >= off) ? tmp[t - off] : 0;
        __syncthreads();
        incl += y;
        tmp[t] = incl;
        __syncthreads();
    }
    if (t < nb) blockoff[t] = incl - s;
}

__global__ __launch_bounds__(256) void k_scan3(int* __restrict__ epos, const int* __restrict__ blockoff,
                                               int* __restrict__ cursor, int n, int nE) {
    int b = blockIdx.x;
    int off = blockoff[b];
    int base = b * 1024 + threadIdx.x * 4;
#pragma unroll
    for (int i = 0; i < 4; ++i) {
        if (base + i < n) {
            int p = epos[base + i] + off;
            epos[base + i] = p;
            cursor[base + i] = p;
        }
    }
    if (b == 0 && threadIdx.x == 0) epos[n] = nE;
}

__global__ void k_scatter(const int* __restrict__ ei, int* __restrict__ cursor,
                          int* __restrict__ srcidx, int nE) {
    int e = blockIdx.x * blockDim.x + threadIdx.x;
    if (e < nE) {
        int c = ei[nE + e];
        int p = atomicAdd(&cursor[c], 1);
        srcidx[p] = ei[e];
    }
}

// ---------- Q(bf16) = x @ W_in^T + b_in  (bf16 MFMA, fp32 accumulate; R7 K32) ----------
__global__ __launch_bounds__(256) void k_in_gemm(
    const float* __restrict__ x, const uint4* __restrict__ Bp,
    const float* __restrict__ bias, unsigned short* __restrict__ qbf, int n) {
    __shared__ uint4 As4[256];
    __shared__ uint4 Bs4[256];
    int tid = threadIdx.x;
    int base = blockIdx.x * 64;
    int lane = tid & 63, w = tid >> 6;

    int srow = tid >> 2;
    int sg = tid & 3;
    int sgs = sg ^ ((srow >> 1) & 3);
    bool rowok = (base + srow) < n;
    const float* xsrc = &x[(size_t)(base + srow) * FIN + sg * 8];

    int arow = 16 * w + (lane & 15);
    int ag = (lane >> 4) ^ ((arow >> 1) & 3);
    int aidx = arow * 4 + ag;
    int kg = lane >> 4;

    f32x4 acc[4];
#pragma unroll
    for (int i = 0; i < 4; ++i) acc[i] = (f32x4){0.f, 0.f, 0.f, 0.f};

    for (int kk = 0; kk < FIN; kk += 32) {
        float4 a0 = make_float4(0.f, 0.f, 0.f, 0.f), a1 = a0;
        if (rowok) {
            a0 = *(const float4*)&xsrc[kk];
            a1 = *(const float4*)&xsrc[kk + 4];
        }
        uint4 bstage = Bp[((kk >> 3) + (tid >> 6)) * 64 + (tid & 63)];
        __syncthreads();
        {
            uint4 u;
            u.x = ((unsigned)f2bf(a0.y) << 16) | f2bf(a0.x);
            u.y = ((unsigned)f2bf(a0.w) << 16) | f2bf(a0.z);
            u.z = ((unsigned)f2bf(a1.y) << 16) | f2bf(a1.x);
            u.w = ((unsigned)f2bf(a1.w) << 16) | f2bf(a1.z);
            As4[srow * 4 + sgs] = u;
            Bs4[tid] = bstage;
        }
        __syncthreads();
        bf16x8 af = *(const bf16x8*)&As4[aidx];
#pragma unroll
        for (int nt = 0; nt < 4; ++nt) {
            bf16x8 bfr = *(const bf16x8*)&Bs4[kg * 64 + nt * 16 + (lane & 15)];
            acc[nt] = __builtin_amdgcn_mfma_f32_16x16x32_bf16(af, bfr, acc[nt], 0, 0, 0);
        }
    }
    int col0 = lane & 15, rowg = lane >> 4;
#pragma unroll
    for (int nt = 0; nt < 4; ++nt) {
        float bv = bias[nt * 16 + col0];
#pragma unroll
        for (int reg = 0; reg < 4; ++reg) {
            int r = base + 16 * w + rowg * 4 + reg;
            if (r < n) qbf[(size_t)r * H + nt * 16 + col0] = f2bf(acc[nt][reg] + bv);
        }
    }
}

// ---------- P = pack(bf16(Q@W1^T), bf16(Q@W2^T)), hl = bf16(relu(Q@Wf^T)) ----------
__global__ __launch_bounds__(256) void k_layer_gemm(
    const uint4* __restrict__ Qbf, const uint4* __restrict__ Bc,
    unsigned* __restrict__ P, unsigned short* __restrict__ hl, int n) {
    __shared__ uint4 Qs[512];
    int tid = threadIdx.x;
    int base = blockIdx.x * 64;
    int lane = tid & 63, w = tid >> 6;
    {
        int r = tid >> 2, g0 = (tid & 3) * 2;
        uint4 u0 = make_uint4(0u, 0u, 0u, 0u), u1 = u0;
        if (base + r < n) {
            u0 = Qbf[(size_t)(base + r) * 8 + g0];
            u1 = Qbf[(size_t)(base + r) * 8 + g0 + 1];
        }
        Qs[r * 8 + (g0 ^ (r & 7))] = u0;
        Qs[r * 8 + ((g0 + 1) ^ (r & 7))] = u1;
    }
    __syncthreads();

    int arow = w * 16 + (lane & 15);
    f32x4 acc[12];
#pragma unroll
    for (int i = 0; i < 12; ++i) acc[i] = (f32x4){0.f, 0.f, 0.f, 0.f};

#pragma unroll
    for (int ks = 0; ks < 2; ++ks) {
        int g = ks * 4 + (lane >> 4);
        bf16x8 af = *(const bf16x8*)&Qs[arow * 8 + (g ^ (arow & 7))];
#pragma unroll
        for (int j = 0; j < 3; ++j) {
#pragma unroll
            for (int nt = 0; nt < 4; ++nt) {
                bf16x8 bfr = *(const bf16x8*)&Bc[(j * 8 + g) * 64 + nt * 16 + (lane & 15)];
                acc[j * 4 + nt] = __builtin_amdgcn_mfma_f32_16x16x32_bf16(af, bfr, acc[j * 4 + nt], 0, 0, 0);
            }
        }
    }
    int col0 = lane & 15, rowg = lane >> 4;
#pragma unroll
    for (int nt = 0; nt < 4; ++nt) {
#pragma unroll
        for (int reg = 0; reg < 4; ++reg) {
            int r = base + w * 16 + rowg * 4 + reg;
            if (r < n) {
                int col = nt * 16 + col0;
                unsigned pv = ((unsigned)f2bf(acc[4 + nt][reg]) << 16) | f2bf(acc[nt][reg]);
                P[(size_t)r * H + col] = pv;
                hl[(size_t)r * H + col] = f2bf(fmaxf(acc[8 + nt][reg], 0.f));
            }
        }
    }
}

// ---------- CSR gather aggregation, 4 edges/iter, depth-3 pipeline (R7 structure) ----------
// Single change vs R7: sigmoid via v_rcp_f32, epilogue via v_rsq_f32.
__global__ __launch_bounds__(256) void k_agg(
    const int* __restrict__ rowptr, const int* __restrict__ srcidx,
    const unsigned* __restrict__ P, const unsigned* __restrict__ hl32,
    unsigned* __restrict__ Qbf32, int n) {
    int tid = threadIdx.x;
    int lane = tid & 63;
    int w = tid >> 6;
    int c = blockIdx.x * 4 + w;
    if (c >= n) return;
    int q = lane >> 4;
    int j = lane & 15;
    const uint4* P4 = (const uint4*)P;

    uint4 pc = P4[(size_t)c * 16 + j];
    float4 h4c = make_float4(bfhi(pc.x), bfhi(pc.y), bfhi(pc.z), bfhi(pc.w));
    float4 acc = make_float4(0.f, 0.f, 0.f, 0.f);

    int k0 = rowptr[c], k1 = rowptr[c + 1];
    if (k0 < k1) {
        const uint4 Z = make_uint4(0u, 0u, 0u, 0u);
        int last = k1 - 1;
        int e0 = k0 + q;
        int sA = srcidx[min(e0, last)];
        bool vA = e0 < k1;
        int sB = srcidx[min(e0 + 4, last)];
        bool vB = (e0 + 4) < k1;
        uint4 pA = P4[(size_t)sA * 16 + j];
        if (!vA) pA = Z;

        for (int kb = k0; kb < k1; kb += 4) {
            int e2 = kb + 8 + q;
            int sC = srcidx[min(e2, last)];
            bool vC = e2 < k1;
            uint4 pB = P4[(size_t)sB * 16 + j];
            if (!vB) pB = Z;
            float4 h3r = make_float4(bflo(pA.x), bflo(pA.y), bflo(pA.z), bflo(pA.w));
            float4 h4r = make_float4(bfhi(pA.x), bfhi(pA.y), bfhi(pA.z), bfhi(pA.w));
            float d = h3r.x * h4c.x + h3r.y * h4c.y + h3r.z * h4c.z + h3r.w * h4c.w;
            d += __shfl_xor(d, 1, 64);
            d += __shfl_xor(d, 2, 64);
            d += __shfl_xor(d, 4, 64);
            d += __shfl_xor(d, 8, 64);
            // sigmoid(-d) = 1/(1+e^d) via v_rcp_f32 (vs ~10-op IEEE divide)
            float s = __builtin_amdgcn_rcpf(1.0f + __expf(d));
            float t = 1.0f - s;
            acc.x += s * h3r.x - t * h4r.x;
            acc.y += s * h3r.y - t * h4r.y;
            acc.z += s * h3r.z - t * h4r.z;
            acc.w += s * h3r.w - t * h4r.w;
            pA = pB; sB = sC; vB = vC;
        }
    }
    acc.x += __shfl_xor(acc.x, 16, 64);
    acc.y += __shfl_xor(acc.y, 16, 64);
    acc.z += __shfl_xor(acc.z, 16, 64);
    acc.w += __shfl_xor(acc.w, 16, 64);
    acc.x += __shfl_xor(acc.x, 32, 64);
    acc.y += __shfl_xor(acc.y, 32, 64);
    acc.z += __shfl_xor(acc.z, 32, 64);
    acc.w += __shfl_xor(acc.w, 32, 64);

    uint2 hv = *(const uint2*)&hl32[(size_t)c * 32 + j * 2];
    acc.x += bflo(hv.x); acc.y += bfhi(hv.x);
    acc.z += bflo(hv.y); acc.w += bfhi(hv.y);

    float ss = acc.x * acc.x + acc.y * acc.y + acc.z * acc.z + acc.w * acc.w;
    ss += __shfl_xor(ss, 1, 64);
    ss += __shfl_xor(ss, 2, 64);
    ss += __shfl_xor(ss, 4, 64);
    ss += __shfl_xor(ss, 8, 64);
    // 1/max(sqrt(ss),1e-12) == min(rsq(ss), 1e12) for ss >= 0
    float inv = fminf(__builtin_amdgcn_rsqf(ss), 1e12f);

    if (lane < 16) {
        uint2 o;
        o.x = ((unsigned)f2bf(acc.y * inv) << 16) | f2bf(acc.x * inv);
        o.y = ((unsigned)f2bf(acc.w * inv) << 16) | f2bf(acc.z * inv);
        *(uint2*)&Qbf32[(size_t)c * 32 + j * 2] = o;
    }
}

// ---------- out = log_softmax(Q@W_out^T + b_out)  (bf16 MFMA head) ----------
__global__ __launch_bounds__(256) void k_head(
    const uint4* __restrict__ Qbf, const uint4* __restrict__ Bo,
    const float* __restrict__ b_out, float* __restrict__ out, int n) {
    __shared__ uint4 Qs[512];
    int tid = threadIdx.x;
    int base = blockIdx.x * 64;
    int lane = tid & 63, w = tid >> 6;
    {
        int r = tid >> 2, g0 = (tid & 3) * 2;
        uint4 u0 = make_uint4(0u, 0u, 0u, 0u), u1 = u0;
        if (base + r < n) {
            u0 = Qbf[(size_t)(base + r) * 8 + g0];
            u1 = Qbf[(size_t)(base + r) * 8 + g0 + 1];
        }
        Qs[r * 8 + (g0 ^ (r & 7))] = u0;
        Qs[r * 8 + ((g0 + 1) ^ (r & 7))] = u1;
    }
    __syncthreads();

    int arow = w * 16 + (lane & 15);
    f32x4 acc[3];
#pragma unroll
    for (int i = 0; i < 3; ++i) acc[i] = (f32x4){0.f, 0.f, 0.f, 0.f};
#pragma unroll
    for (int ks = 0; ks < 2; ++ks) {
        int g = ks * 4 + (lane >> 4);
        bf16x8 af = *(const bf16x8*)&Qs[arow * 8 + (g ^ (arow & 7))];
#pragma unroll
        for (int nt = 0; nt < 3; ++nt) {
            bf16x8 bfr = *(const bf16x8*)&Bo[g * 64 + nt * 16 + (lane & 15)];
            acc[nt] = __builtin_amdgcn_mfma_f32_16x16x32_bf16(af, bfr, acc[nt], 0, 0, 0);
        }
    }
    int col = lane & 15, rowg = lane >> 4;
    float bv0 = b_out[col];
    float bv1 = b_out[16 + col];
    float bv2 = (col < 8) ? b_out[32 + col] : 0.f;
#pragma unroll
    for (int reg = 0; reg < 4; ++reg) {
        int r = base + w * 16 + rowg * 4 + reg;
        float v0 = acc[0][reg] + bv0;
        float v1 = acc[1][reg] + bv1;
        float v2 = (col < 8) ? (acc[2][reg] + bv2) : -3.0e38f;
        float m = fmaxf(fmaxf(v0, v1), v2);
        m = fmaxf(m, __shfl_xor(m, 1, 64));
        m = fmaxf(m, __shfl_xor(m, 2, 64));
        m = fmaxf(m, __shfl_xor(m, 4, 64));
        m = fmaxf(m, __shfl_xor(m, 8, 64));
        float ex = __expf(v0 - m) + __expf(v1 - m) + ((col < 8) ? __expf(v2 - m) : 0.f);
        ex += __shfl_xor(ex, 1, 64);
        ex += __shfl_xor(ex, 2, 64);
        ex += __shfl_xor(ex, 4, 64);
        ex += __shfl_xor(ex, 8, 64);
        float lse = m + logf(ex);
        if (r < n) {
            out[(size_t)r * COUT + col] = v0 - lse;
            out[(size_t)r * COUT + 16 + col] = v1 - lse;
            if (col < 8) out[(size_t)r * COUT + 32 + col] = v2 - lse;
        }
    }
}

extern "C" void kernel_launch(void* const* d_in, const int* in_sizes, int n_in,
                              void* d_out, int out_size, void* d_ws, size_t ws_size,
                              hipStream_t stream) {
    const float* x     = (const float*)d_in[0];
    const int*   ei    = (const int*)d_in[1];
    const float* W_in  = (const float*)d_in[2];
    const float* b_in  = (const float*)d_in[3];
    const float* W1_0  = (const float*)d_in[4];
    const float* W2_0  = (const float*)d_in[5];
    const float* Wf_0  = (const float*)d_in[6];
    const float* W1_1  = (const float*)d_in[7];
    const float* W2_1  = (const float*)d_in[8];
    const float* Wf_1  = (const float*)d_in[9];
    const float* W_out = (const float*)d_in[10];
    const float* b_out = (const float*)d_in[11];
    float* out = (float*)d_out;

    int N = in_sizes[0] / FIN;
    int E = in_sizes[1] / 2;

    uint4* Bp    = (uint4*)d_ws;                     // 4096 uint4
    uint4* Bc0   = Bp + 4096;                        // 1536
    uint4* Bc1   = Bc0 + 1536;                       // 1536
    uint4* Bo    = Bc1 + 1536;                       // 512
    unsigned* Qbf32 = (unsigned*)(Bo + 512);         // N*32 u32 (bf16 Q)
    unsigned* P  = Qbf32 + (size_t)N * 32;           // N*64 u32 (packed h4|h3)
    unsigned* hl32 = P + (size_t)N * H;              // N*32 u32 (bf16 hloop)
    int* rowptr  = (int*)(hl32 + (size_t)N * 32);    // N+2
    int* deg     = rowptr + (N + 2);
    int* cursor  = deg + N;
    int* srcidx  = cursor + N;
    int* blocksum = srcidx + E;
    int* blockoff = blocksum + 256;

    k_pack<<<30, 256, 0, stream>>>(W_in, W1_0, W2_0, Wf_0, W1_1, W2_1, Wf_1, W_out,
                                   Bp, Bc0, Bc1, Bo);

    int nb = (N + 1023) / 1024;
    hipMemsetAsync(deg, 0, (size_t)N * sizeof(int), stream);
    k_hist<<<(E + 255) / 256, 256, 0, stream>>>(ei, deg, E);
    k_scan1<<<nb, 256, 0, stream>>>(deg, rowptr, blocksum, N);
    k_scan2<<<1, 256, 0, stream>>>(blocksum, blockoff, nb);
    k_scan3<<<nb, 256, 0, stream>>>(rowptr, blockoff, cursor, N, E);
    k_scatter<<<(E + 255) / 256, 256, 0, stream>>>(ei, cursor, srcidx, E);

    int gm = (N + 63) / 64;
    k_in_gemm<<<gm, 256, 0, stream>>>(x, Bp, b_in, (unsigned short*)Qbf32, N);

    int ga = (N + 3) / 4;
    // layer 0
    k_layer_gemm<<<gm, 256, 0, stream>>>((const uint4*)Qbf32, Bc0, P, (unsigned short*)hl32, N);
    k_agg<<<ga, 256, 0, stream>>>(rowptr, srcidx, P, hl32, Qbf32, N);
    // layer 1
    k_layer_gemm<<<gm, 256, 0, stream>>>((const uint4*)Qbf32, Bc1, P, (unsigned short*)hl32, N);
    k_agg<<<ga, 256, 0, stream>>>(rowptr, srcidx, P, hl32, Qbf32, N);
    // output head
    k_head<<<gm, 256, 0, stream>>>((const uint4*)Qbf32, Bo, b_out, out, N);
}

// Round 14
// 355.952 us; speedup vs baseline: 1.0405x; 1.0405x over previous
//
#include <hip/hip_runtime.h>
#include <hip/hip_bf16.h>
#include <math.h>

#define H 64
#define FIN 512
#define COUT 40

typedef __attribute__((ext_vector_type(8))) short bf16x8;
typedef __attribute__((ext_vector_type(4))) float f32x4;

__device__ __forceinline__ unsigned short f2bf(float f) {
    union { float f; unsigned u; } v; v.f = f;
    unsigned r = v.u + 0x7FFF + ((v.u >> 16) & 1);   // RNE
    return (unsigned short)(r >> 16);
}
__device__ __forceinline__ float bflo(unsigned u) { return __uint_as_float(u << 16); }
__device__ __forceinline__ float bfhi(unsigned u) { return __uint_as_float(u & 0xffff0000u); }

// ---------- unified weight pack: Bp (W_in), Bc0/Bc1 (layers), Bo (W_out, 48-col padded) ----------
__global__ void k_pack(const float* __restrict__ W_in,
                       const float* __restrict__ W1_0, const float* __restrict__ W2_0,
                       const float* __restrict__ Wf_0,
                       const float* __restrict__ W1_1, const float* __restrict__ W2_1,
                       const float* __restrict__ Wf_1,
                       const float* __restrict__ W_out,
                       uint4* __restrict__ Bp, uint4* __restrict__ Bc0,
                       uint4* __restrict__ Bc1, uint4* __restrict__ Bo) {
    int t = blockIdx.x * blockDim.x + threadIdx.x;
    const float* src;
    uint4* dst;
    if (t < 4096) {                       // W_in: 64 kb x 64 n
        int kb = t >> 6, n = t & 63;
        src = &W_in[n * FIN + kb * 8];
        dst = &Bp[t];
    } else if (t < 4096 + 1536) {         // layer 0
        int u = t - 4096;
        int j = u >> 9, kb = (u >> 6) & 7, n = u & 63;
        const float* W = (j == 0) ? W1_0 : (j == 1) ? W2_0 : Wf_0;
        src = &W[n * H + kb * 8];
        dst = &Bc0[u];
    } else if (t < 4096 + 3072) {         // layer 1
        int u = t - 4096 - 1536;
        int j = u >> 9, kb = (u >> 6) & 7, n = u & 63;
        const float* W = (j == 0) ? W1_1 : (j == 1) ? W2_1 : Wf_1;
        src = &W[n * H + kb * 8];
        dst = &Bc1[u];
    } else if (t < 4096 + 3072 + 512) {   // W_out: 8 kb x 64 cols (cols >= COUT -> 0)
        int u = t - 4096 - 3072;
        int kb = u >> 6, col = u & 63;
        if (col >= COUT) { Bo[u] = make_uint4(0u, 0u, 0u, 0u); return; }
        src = &W_out[col * H + kb * 8];
        dst = &Bo[u];
    } else return;
    float4 a0 = *(const float4*)&src[0];
    float4 a1 = *(const float4*)&src[4];
    uint4 u;
    u.x = ((unsigned)f2bf(a0.y) << 16) | f2bf(a0.x);
    u.y = ((unsigned)f2bf(a0.w) << 16) | f2bf(a0.z);
    u.z = ((unsigned)f2bf(a1.y) << 16) | f2bf(a1.x);
    u.w = ((unsigned)f2bf(a1.w) << 16) | f2bf(a1.z);
    *dst = u;
}

// ---------- CSR build ----------
__global__ void k_zero(int* __restrict__ p, int n) {
    int i = blockIdx.x * blockDim.x + threadIdx.x;
    if (i < n) p[i] = 0;
}

__global__ void k_hist(const int* __restrict__ ei, int* __restrict__ deg, int nE) {
    int e = blockIdx.x * blockDim.x + threadIdx.x;
    if (e < nE) atomicAdd(&deg[ei[nE + e]], 1);
}

__global__ __launch_bounds__(256) void k_scan1(const int* __restrict__ deg, int* __restrict__ epos,
                                               int* __restrict__ blocksum, int n) {
    __shared__ int tmp[256];
    int t = threadIdx.x;
    int base = blockIdx.x * 1024 + t * 4;
    int v[4]; int s = 0;
#pragma unroll
    for (int i = 0; i < 4; ++i) { v[i] = (base + i < n) ? deg[base + i] : 0; s += v[i]; }
    tmp[t] = s;
    __syncthreads();
    int incl = s;
    for (int off = 1; off < 256; off <<= 1) {
        int y = (t >= off) ? tmp[t - off] : 0;
        __syncthreads();
        incl += y;
        tmp[t] = incl;
        __syncthreads();
    }
    if (t == 255) blocksum[blockIdx.x] = incl;
    int run = incl - s;
#pragma unroll
    for (int i = 0; i < 4; ++i) { if (base + i < n) epos[base + i] = run; run += v[i]; }
}

__global__ __launch_bounds__(256) void k_scan2(const int* __restrict__ blocksum,
                                               int* __restrict__ blockoff, int nb) {
    __shared__ int tmp[256];
    int t = threadIdx.x;
    int s = (t < nb) ? blocksum[t] : 0;
    tmp[t] = s;
    __syncthreads();
    int incl = s;
    for (int off = 1; off < 256; off <<= 1) {
        int y = (t >= off) ? tmp[t - off] : 0;
        __syncthreads();
        incl += y;
        tmp[t] = incl;
        __syncthreads();
    }
    if (t < nb) blockoff[t] = incl - s;
}

__global__ __launch_bounds__(256) void k_scan3(int* __restrict__ epos, const int* __restrict__ blockoff,
                                               int* __restrict__ cursor, int n, int nE) {
    int b = blockIdx.x;
    int off = blockoff[b];
    int base = b * 1024 + threadIdx.x * 4;
#pragma unroll
    for (int i = 0; i < 4; ++i) {
        if (base + i < n) {
            int p = epos[base + i] + off;
            epos[base + i] = p;
            cursor[base + i] = p;
        }
    }
    if (b == 0 && threadIdx.x == 0) epos[n] = nE;
}

__global__ void k_scatter(const int* __restrict__ ei, int* __restrict__ cursor,
                          int* __restrict__ srcidx, int nE) {
    int e = blockIdx.x * blockDim.x + threadIdx.x;
    if (e < nE) {
        int c = ei[nE + e];
        int p = atomicAdd(&cursor[c], 1);
        srcidx[p] = ei[e];
    }
}

// ---------- Q(bf16) = x @ W_in^T + b_in  (bf16 MFMA, K-step 64, 8 iters) ----------
__global__ __launch_bounds__(256) void k_in_gemm(
    const float* __restrict__ x, const uint4* __restrict__ Bp,
    const float* __restrict__ bias, unsigned short* __restrict__ qbf, int n) {
    __shared__ uint4 As4[512];   // 64 rows x 8 granules, XOR-swizzled
    __shared__ uint4 Bs4[512];   // [g 0..7][col 0..63]
    int tid = threadIdx.x;
    int base = blockIdx.x * 64;
    int lane = tid & 63, w = tid >> 6;

    int srow = tid >> 2;            // 0..63
    int g0 = (tid & 3) * 2;         // granules g0, g0+1 (granule = 8 k-floats)
    bool rowok = (base + srow) < n;
    const float* xsrc = &x[(size_t)(base + srow) * FIN + g0 * 8];

    int arow = 16 * w + (lane & 15);
    int kg = lane >> 4;
    int l15 = lane & 15;

    f32x4 acc[4];
#pragma unroll
    for (int i = 0; i < 4; ++i) acc[i] = (f32x4){0.f, 0.f, 0.f, 0.f};

    for (int kk = 0; kk < FIN; kk += 64) {
        float4 a0 = make_float4(0.f,0.f,0.f,0.f), a1 = a0, a2 = a0, a3 = a0;
        if (rowok) {
            a0 = *(const float4*)&xsrc[kk];
            a1 = *(const float4*)&xsrc[kk + 4];
            a2 = *(const float4*)&xsrc[kk + 8];
            a3 = *(const float4*)&xsrc[kk + 12];
        }
        uint4 b0 = Bp[(kk >> 3) * 64 + tid];
        uint4 b1 = Bp[(kk >> 3) * 64 + tid + 256];
        __syncthreads();
        {
            uint4 u0, u1;
            u0.x = ((unsigned)f2bf(a0.y) << 16) | f2bf(a0.x);
            u0.y = ((unsigned)f2bf(a0.w) << 16) | f2bf(a0.z);
            u0.z = ((unsigned)f2bf(a1.y) << 16) | f2bf(a1.x);
            u0.w = ((unsigned)f2bf(a1.w) << 16) | f2bf(a1.z);
            u1.x = ((unsigned)f2bf(a2.y) << 16) | f2bf(a2.x);
            u1.y = ((unsigned)f2bf(a2.w) << 16) | f2bf(a2.z);
            u1.z = ((unsigned)f2bf(a3.y) << 16) | f2bf(a3.x);
            u1.w = ((unsigned)f2bf(a3.w) << 16) | f2bf(a3.z);
            As4[srow * 8 + (g0 ^ (srow & 7))] = u0;
            As4[srow * 8 + ((g0 + 1) ^ (srow & 7))] = u1;
            Bs4[tid] = b0;
            Bs4[tid + 256] = b1;
        }
        __syncthreads();
#pragma unroll
        for (int ks = 0; ks < 2; ++ks) {
            int g = ks * 4 + kg;
            bf16x8 af = *(const bf16x8*)&As4[arow * 8 + (g ^ (arow & 7))];
#pragma unroll
            for (int nt = 0; nt < 4; ++nt) {
                bf16x8 bfr = *(const bf16x8*)&Bs4[g * 64 + nt * 16 + l15];
                acc[nt] = __builtin_amdgcn_mfma_f32_16x16x32_bf16(af, bfr, acc[nt], 0, 0, 0);
            }
        }
    }
    int col0 = l15, rowg = lane >> 4;
#pragma unroll
    for (int nt = 0; nt < 4; ++nt) {
        float bv = bias[nt * 16 + col0];
#pragma unroll
        for (int reg = 0; reg < 4; ++reg) {
            int r = base + 16 * w + rowg * 4 + reg;
            if (r < n) qbf[(size_t)r * H + nt * 16 + col0] = f2bf(acc[nt][reg] + bv);
        }
    }
}

// ---------- P = pack(bf16(Q@W1^T), bf16(Q@W2^T)), hl = bf16(relu(Q@Wf^T)) ----------
__global__ __launch_bounds__(256) void k_layer_gemm(
    const uint4* __restrict__ Qbf, const uint4* __restrict__ Bc,
    unsigned* __restrict__ P, unsigned short* __restrict__ hl, int n) {
    __shared__ uint4 Qs[512];
    int tid = threadIdx.x;
    int base = blockIdx.x * 64;
    int lane = tid & 63, w = tid >> 6;
    {
        int r = tid >> 2, g0 = (tid & 3) * 2;
        uint4 u0 = make_uint4(0u, 0u, 0u, 0u), u1 = u0;
        if (base + r < n) {
            u0 = Qbf[(size_t)(base + r) * 8 + g0];
            u1 = Qbf[(size_t)(base + r) * 8 + g0 + 1];
        }
        Qs[r * 8 + (g0 ^ (r & 7))] = u0;
        Qs[r * 8 + ((g0 + 1) ^ (r & 7))] = u1;
    }
    __syncthreads();

    int arow = w * 16 + (lane & 15);
    f32x4 acc[12];
#pragma unroll
    for (int i = 0; i < 12; ++i) acc[i] = (f32x4){0.f, 0.f, 0.f, 0.f};

#pragma unroll
    for (int ks = 0; ks < 2; ++ks) {
        int g = ks * 4 + (lane >> 4);
        bf16x8 af = *(const bf16x8*)&Qs[arow * 8 + (g ^ (arow & 7))];
#pragma unroll
        for (int j = 0; j < 3; ++j) {
#pragma unroll
            for (int nt = 0; nt < 4; ++nt) {
                bf16x8 bfr = *(const bf16x8*)&Bc[(j * 8 + g) * 64 + nt * 16 + (lane & 15)];
                acc[j * 4 + nt] = __builtin_amdgcn_mfma_f32_16x16x32_bf16(af, bfr, acc[j * 4 + nt], 0, 0, 0);
            }
        }
    }
    int col0 = lane & 15, rowg = lane >> 4;
#pragma unroll
    for (int nt = 0; nt < 4; ++nt) {
#pragma unroll
        for (int reg = 0; reg < 4; ++reg) {
            int r = base + w * 16 + rowg * 4 + reg;
            if (r < n) {
                int col = nt * 16 + col0;
                unsigned pv = ((unsigned)f2bf(acc[4 + nt][reg]) << 16) | f2bf(acc[nt][reg]);
                P[(size_t)r * H + col] = pv;
                hl[(size_t)r * H + col] = f2bf(fmaxf(acc[8 + nt][reg], 0.f));
            }
        }
    }
}

// ---------- CSR gather aggregation, 4 edges/iter, depth-3 pipeline (R7 verbatim) ----------
__global__ __launch_bounds__(256) void k_agg(
    const int* __restrict__ rowptr, const int* __restrict__ srcidx,
    const unsigned* __restrict__ P, const unsigned* __restrict__ hl32,
    unsigned* __restrict__ Qbf32, int n) {
    int tid = threadIdx.x;
    int lane = tid & 63;
    int w = tid >> 6;
    int c = blockIdx.x * 4 + w;
    if (c >= n) return;
    int q = lane >> 4;
    int j = lane & 15;
    const uint4* P4 = (const uint4*)P;

    uint4 pc = P4[(size_t)c * 16 + j];
    float4 h4c = make_float4(bfhi(pc.x), bfhi(pc.y), bfhi(pc.z), bfhi(pc.w));
    float4 acc = make_float4(0.f, 0.f, 0.f, 0.f);

    int k0 = rowptr[c], k1 = rowptr[c + 1];
    if (k0 < k1) {
        const uint4 Z = make_uint4(0u, 0u, 0u, 0u);
        int last = k1 - 1;
        int e0 = k0 + q;
        int sA = srcidx[min(e0, last)];
        bool vA = e0 < k1;
        int sB = srcidx[min(e0 + 4, last)];
        bool vB = (e0 + 4) < k1;
        uint4 pA = P4[(size_t)sA * 16 + j];
        if (!vA) pA = Z;

        for (int kb = k0; kb < k1; kb += 4) {
            int e2 = kb + 8 + q;
            int sC = srcidx[min(e2, last)];
            bool vC = e2 < k1;
            uint4 pB = P4[(size_t)sB * 16 + j];
            if (!vB) pB = Z;
            float4 h3r = make_float4(bflo(pA.x), bflo(pA.y), bflo(pA.z), bflo(pA.w));
            float4 h4r = make_float4(bfhi(pA.x), bfhi(pA.y), bfhi(pA.z), bfhi(pA.w));
            float d = h3r.x * h4c.x + h3r.y * h4c.y + h3r.z * h4c.z + h3r.w * h4c.w;
            d += __shfl_xor(d, 1, 64);
            d += __shfl_xor(d, 2, 64);
            d += __shfl_xor(d, 4, 64);
            d += __shfl_xor(d, 8, 64);
            float s = 1.0f / (1.0f + __expf(d));   // sigmoid(-d)
            float t = 1.0f - s;
            acc.x += s * h3r.x - t * h4r.x;
            acc.y += s * h3r.y - t * h4r.y;
            acc.z += s * h3r.z - t * h4r.z;
            acc.w += s * h3r.w - t * h4r.w;
            pA = pB; sB = sC; vB = vC;
        }
    }
    acc.x += __shfl_xor(acc.x, 16, 64);
    acc.y += __shfl_xor(acc.y, 16, 64);
    acc.z += __shfl_xor(acc.z, 16, 64);
    acc.w += __shfl_xor(acc.w, 16, 64);
    acc.x += __shfl_xor(acc.x, 32, 64);
    acc.y += __shfl_xor(acc.y, 32, 64);
    acc.z += __shfl_xor(acc.z, 32, 64);
    acc.w += __shfl_xor(acc.w, 32, 64);

    uint2 hv = *(const uint2*)&hl32[(size_t)c * 32 + j * 2];
    acc.x += bflo(hv.x); acc.y += bfhi(hv.x);
    acc.z += bflo(hv.y); acc.w += bfhi(hv.y);

    float ss = acc.x * acc.x + acc.y * acc.y + acc.z * acc.z + acc.w * acc.w;
    ss += __shfl_xor(ss, 1, 64);
    ss += __shfl_xor(ss, 2, 64);
    ss += __shfl_xor(ss, 4, 64);
    ss += __shfl_xor(ss, 8, 64);
    float inv = 1.0f / fmaxf(sqrtf(ss), 1e-12f);

    if (lane < 16) {
        uint2 o;
        o.x = ((unsigned)f2bf(acc.y * inv) << 16) | f2bf(acc.x * inv);
        o.y = ((unsigned)f2bf(acc.w * inv) << 16) | f2bf(acc.z * inv);
        *(uint2*)&Qbf32[(size_t)c * 32 + j * 2] = o;
    }
}

// ---------- out = log_softmax(Q@W_out^T + b_out)  (bf16 MFMA head) ----------
__global__ __launch_bounds__(256) void k_head(
    const uint4* __restrict__ Qbf, const uint4* __restrict__ Bo,
    const float* __restrict__ b_out, float* __restrict__ out, int n) {
    __shared__ uint4 Qs[512];
    int tid = threadIdx.x;
    int base = blockIdx.x * 64;
    int lane = tid & 63, w = tid >> 6;
    {
        int r = tid >> 2, g0 = (tid & 3) * 2;
        uint4 u0 = make_uint4(0u, 0u, 0u, 0u), u1 = u0;
        if (base + r < n) {
            u0 = Qbf[(size_t)(base + r) * 8 + g0];
            u1 = Qbf[(size_t)(base + r) * 8 + g0 + 1];
        }
        Qs[r * 8 + (g0 ^ (r & 7))] = u0;
        Qs[r * 8 + ((g0 + 1) ^ (r & 7))] = u1;
    }
    __syncthreads();

    int arow = w * 16 + (lane & 15);
    f32x4 acc[3];
#pragma unroll
    for (int i = 0; i < 3; ++i) acc[i] = (f32x4){0.f, 0.f, 0.f, 0.f};
#pragma unroll
    for (int ks = 0; ks < 2; ++ks) {
        int g = ks * 4 + (lane >> 4);
        bf16x8 af = *(const bf16x8*)&Qs[arow * 8 + (g ^ (arow & 7))];
#pragma unroll
        for (int nt = 0; nt < 3; ++nt) {
            bf16x8 bfr = *(const bf16x8*)&Bo[g * 64 + nt * 16 + (lane & 15)];
            acc[nt] = __builtin_amdgcn_mfma_f32_16x16x32_bf16(af, bfr, acc[nt], 0, 0, 0);
        }
    }
    int col = lane & 15, rowg = lane >> 4;
    float bv0 = b_out[col];
    float bv1 = b_out[16 + col];
    float bv2 = (col < 8) ? b_out[32 + col] : 0.f;
#pragma unroll
    for (int reg = 0; reg < 4; ++reg) {
        int r = base + w * 16 + rowg * 4 + reg;
        float v0 = acc[0][reg] + bv0;
        float v1 = acc[1][reg] + bv1;
        float v2 = (col < 8) ? (acc[2][reg] + bv2) : -3.0e38f;
        float m = fmaxf(fmaxf(v0, v1), v2);
        m = fmaxf(m, __shfl_xor(m, 1, 64));
        m = fmaxf(m, __shfl_xor(m, 2, 64));
        m = fmaxf(m, __shfl_xor(m, 4, 64));
        m = fmaxf(m, __shfl_xor(m, 8, 64));
        float ex = __expf(v0 - m) + __expf(v1 - m) + ((col < 8) ? __expf(v2 - m) : 0.f);
        ex += __shfl_xor(ex, 1, 64);
        ex += __shfl_xor(ex, 2, 64);
        ex += __shfl_xor(ex, 4, 64);
        ex += __shfl_xor(ex, 8, 64);
        float lse = m + logf(ex);
        if (r < n) {
            out[(size_t)r * COUT + col] = v0 - lse;
            out[(size_t)r * COUT + 16 + col] = v1 - lse;
            if (col < 8) out[(size_t)r * COUT + 32 + col] = v2 - lse;
        }
    }
}

extern "C" void kernel_launch(void* const* d_in, const int* in_sizes, int n_in,
                              void* d_out, int out_size, void* d_ws, size_t ws_size,
                              hipStream_t stream) {
    const float* x     = (const float*)d_in[0];
    const int*   ei    = (const int*)d_in[1];
    const float* W_in  = (const float*)d_in[2];
    const float* b_in  = (const float*)d_in[3];
    const float* W1_0  = (const float*)d_in[4];
    const float* W2_0  = (const float*)d_in[5];
    const float* Wf_0  = (const float*)d_in[6];
    const float* W1_1  = (const float*)d_in[7];
    const float* W2_1  = (const float*)d_in[8];
    const float* Wf_1  = (const float*)d_in[9];
    const float* W_out = (const float*)d_in[10];
    const float* b_out = (const float*)d_in[11];
    float* out = (float*)d_out;

    int N = in_sizes[0] / FIN;
    int E = in_sizes[1] / 2;

    uint4* Bp    = (uint4*)d_ws;                     // 4096 uint4
    uint4* Bc0   = Bp + 4096;                        // 1536
    uint4* Bc1   = Bc0 + 1536;                       // 1536
    uint4* Bo    = Bc1 + 1536;                       // 512
    unsigned* Qbf32 = (unsigned*)(Bo + 512);         // N*32 u32 (bf16 Q)
    unsigned* P  = Qbf32 + (size_t)N * 32;           // N*64 u32 (packed h4|h3)
    unsigned* hl32 = P + (size_t)N * H;              // N*32 u32 (bf16 hloop)
    int* rowptr  = (int*)(hl32 + (size_t)N * 32);    // N+2
    int* deg     = rowptr + (N + 2);
    int* cursor  = deg + N;
    int* srcidx  = cursor + N;
    int* blocksum = srcidx + E;
    int* blockoff = blocksum + 256;

    k_pack<<<30, 256, 0, stream>>>(W_in, W1_0, W2_0, Wf_0, W1_1, W2_1, Wf_1, W_out,
                                   Bp, Bc0, Bc1, Bo);

    int nb = (N + 1023) / 1024;
    k_zero<<<(N + 255) / 256, 256, 0, stream>>>(deg, N);
    k_hist<<<(E + 255) / 256, 256, 0, stream>>>(ei, deg, E);
    k_scan1<<<nb, 256, 0, stream>>>(deg, rowptr, blocksum, N);
    k_scan2<<<1, 256, 0, stream>>>(blocksum, blockoff, nb);
    k_scan3<<<nb, 256, 0, stream>>>(rowptr, blockoff, cursor, N, E);
    k_scatter<<<(E + 255) / 256, 256, 0, stream>>>(ei, cursor, srcidx, E);

    int gm = (N + 63) / 64;
    k_in_gemm<<<gm, 256, 0, stream>>>(x, Bp, b_in, (unsigned short*)Qbf32, N);

    int ga = (N + 3) / 4;
    // layer 0
    k_layer_gemm<<<gm, 256, 0, stream>>>((const uint4*)Qbf32, Bc0, P, (unsigned short*)hl32, N);
    k_agg<<<ga, 256, 0, stream>>>(rowptr, srcidx, P, hl32, Qbf32, N);
    // layer 1
    k_layer_gemm<<<gm, 256, 0, stream>>>((const uint4*)Qbf32, Bc1, P, (unsigned short*)hl32, N);
    k_agg<<<ga, 256, 0, stream>>>(rowptr, srcidx, P, hl32, Qbf32, N);
    // output head
    k_head<<<gm, 256, 0, stream>>>((const uint4*)Qbf32, Bo, b_out, out, N);
}